// Round 1
// baseline (500.245 us; speedup 1.0000x reference)
//
#include <hip/hip_runtime.h>
#include <math.h>

#define C_DIM 256
#define N_DIM 19
#define HW 65536
#define PP_OFF (N_DIM * C_DIM)      /* 4864 */
#define PA_OFF (PP_OFF + 32)
#define AN_OFF (PP_OFF + 64)

// ---------------- prep: per-n scalars + normalized A rows into ws ----------
__global__ void prep_kernel(const float* __restrict__ P,
                            const float* __restrict__ A,
                            float* __restrict__ ws) {
    int n = blockIdx.x;          // one wave per n
    int lane = threadIdx.x;      // 64 lanes
    float pp = 0.f, aa = 0.f, pa = 0.f;
    for (int c = lane; c < C_DIM; c += 64) {
        float p = P[n * C_DIM + c];
        float a = A[n * C_DIM + c];
        pp += p * p;
        aa += a * a;
        pa += p * a;
    }
#pragma unroll
    for (int off = 32; off > 0; off >>= 1) {
        pp += __shfl_xor(pp, off);
        aa += __shfl_xor(aa, off);
        pa += __shfl_xor(pa, off);
    }
    float an  = sqrtf(aa);
    float inv = 1.0f / fmaxf(an, 1e-12f);
    for (int c = lane; c < C_DIM; c += 64) {
        ws[n * C_DIM + c] = A[n * C_DIM + c] * inv;   // normed_A
    }
    if (lane == 0) {
        ws[PP_OFF + n] = pp;
        ws[PA_OFF + n] = -pa * inv;   // sum(-P * normed_A)
        ws[AN_OFF + n] = an;          // ||A_n||
    }
}

// ---------------- main: 2 pixels per thread, full C reduction --------------
__global__ __launch_bounds__(256) void hyper_mlr_main(
    const float* __restrict__ x, const float* __restrict__ P,
    const float* __restrict__ ws, float* __restrict__ out)
{
    __shared__ float sP[N_DIM * C_DIM];   // -P
    __shared__ float sA[N_DIM * C_DIM];   // normed_A
    for (int i = threadIdx.x; i < N_DIM * C_DIM; i += 256) {
        sP[i] = -P[i];
        sA[i] = ws[i];
    }
    __syncthreads();

    int tid = blockIdx.x * 256 + threadIdx.x;
    int s   = tid * 2;              // first pixel of the pair
    int b   = s >> 16;              // / (H*W)
    int hw  = s & 65535;
    const float* xb = x + (size_t)b * C_DIM * HW + hw;

    float xx0 = 0.f, xx1 = 0.f;
    float px0[N_DIM], px1[N_DIM], xa0[N_DIM], xa1[N_DIM];
#pragma unroll
    for (int n = 0; n < N_DIM; ++n) { px0[n] = px1[n] = xa0[n] = xa1[n] = 0.f; }

#pragma unroll 4
    for (int c = 0; c < C_DIM; c += 2) {
        float2 v0 = *reinterpret_cast<const float2*>(xb + (size_t)c * HW);
        float2 v1 = *reinterpret_cast<const float2*>(xb + (size_t)(c + 1) * HW);
        xx0 += v0.x * v0.x; xx0 += v1.x * v1.x;
        xx1 += v0.y * v0.y; xx1 += v1.y * v1.y;
#pragma unroll
        for (int n = 0; n < N_DIM; ++n) {
            float2 p = *reinterpret_cast<const float2*>(&sP[n * C_DIM + c]);
            float2 a = *reinterpret_cast<const float2*>(&sA[n * C_DIM + c]);
            px0[n] += v0.x * p.x; px0[n] += v1.x * p.y;
            px1[n] += v0.y * p.x; px1[n] += v1.y * p.y;
            xa0[n] += v0.x * a.x; xa0[n] += v1.x * a.y;
            xa1[n] += v0.y * a.x; xa1[n] += v1.y * a.y;
        }
    }

    const float K        = 0.5f;
    const float sqK      = 0.70710678118654752f;          // sqrt(K)
    const float maxnorm  = 0.999f / sqK;                  // (1-PROJ_EPS)/sqrt(K)
    const float maxnorm2 = maxnorm * maxnorm;
    const float eps      = 1e-12f;

    float* ob = out + (size_t)b * N_DIM * HW + hw;
#pragma unroll
    for (int n = 0; n < N_DIM; ++n) {
        float pp = ws[PP_OFF + n];
        float pa = ws[PA_OFF + n];
        float an = ws[AN_OFF + n];
        float o0, o1;
        float pxs0 = px0[n], pxs1 = px1[n];
        float xas0 = xa0[n], xas1 = xa1[n];
        {
            float px = pxs0, xa = xas0, xx = xx0;
            float Av = 1.0f + px + K * xx;                 // 2K = 1
            float Bv = 1.0f - K * pp;
            float D  = fmaxf(1.0f + px + (K * K) * xx * pp, eps);
            float alpha = Av / D, beta = Bv / D;
            float mob = alpha * alpha * pp + beta * beta * xx + 2.0f * alpha * beta * px;
            float sqrtm = sqrtf(fmaxf(mob, 0.0f));
            float proj = (sqrtm > maxnorm) ? (maxnorm / fmaxf(sqrtm, eps)) : 1.0f;
            float mobp = (sqrtm < maxnorm) ? mob : maxnorm2;
            float mobdota = (beta * xa + alpha * pa) * proj;
            float lamb = 2.0f / fmaxf(1.0f - K * mobp, eps);
            float sine = sqK * mobdota * lamb;
            o0 = (2.0f / sqK) * an * asinhf(sine);
        }
        {
            float px = pxs1, xa = xas1, xx = xx1;
            float Av = 1.0f + px + K * xx;
            float Bv = 1.0f - K * pp;
            float D  = fmaxf(1.0f + px + (K * K) * xx * pp, eps);
            float alpha = Av / D, beta = Bv / D;
            float mob = alpha * alpha * pp + beta * beta * xx + 2.0f * alpha * beta * px;
            float sqrtm = sqrtf(fmaxf(mob, 0.0f));
            float proj = (sqrtm > maxnorm) ? (maxnorm / fmaxf(sqrtm, eps)) : 1.0f;
            float mobp = (sqrtm < maxnorm) ? mob : maxnorm2;
            float mobdota = (beta * xa + alpha * pa) * proj;
            float lamb = 2.0f / fmaxf(1.0f - K * mobp, eps);
            float sine = sqK * mobdota * lamb;
            o1 = (2.0f / sqK) * an * asinhf(sine);
        }
        *reinterpret_cast<float2*>(ob + (size_t)n * HW) = make_float2(o0, o1);
    }
}

extern "C" void kernel_launch(void* const* d_in, const int* in_sizes, int n_in,
                              void* d_out, int out_size, void* d_ws, size_t ws_size,
                              hipStream_t stream) {
    const float* x  = (const float*)d_in[0];
    const float* P  = (const float*)d_in[1];
    const float* A  = (const float*)d_in[2];
    float* out = (float*)d_out;
    float* ws  = (float*)d_ws;

    prep_kernel<<<N_DIM, 64, 0, stream>>>(P, A, ws);
    hyper_mlr_main<<<512, 256, 0, stream>>>(x, P, ws, out);
}

// Round 2
// 434.607 us; speedup vs baseline: 1.1510x; 1.1510x over previous
//
#include <hip/hip_runtime.h>
#include <math.h>

#define C_DIM 256
#define N_DIM 19
#define HW 65536
#define CQ 64                      /* C_DIM/4 */
#define PP_OFF (N_DIM * C_DIM)     /* 4864 */
#define PA_OFF (PP_OFF + 32)
#define AN_OFF (PP_OFF + 64)

// ---------------- prep: per-n scalars + normalized A rows into ws ----------
__global__ void prep_kernel(const float* __restrict__ P,
                            const float* __restrict__ A,
                            float* __restrict__ ws) {
    int n = blockIdx.x;          // one wave per n
    int lane = threadIdx.x;      // 64 lanes
    float pp = 0.f, aa = 0.f, pa = 0.f;
    for (int c = lane; c < C_DIM; c += 64) {
        float p = P[n * C_DIM + c];
        float a = A[n * C_DIM + c];
        pp += p * p;
        aa += a * a;
        pa += p * a;
    }
#pragma unroll
    for (int off = 32; off > 0; off >>= 1) {
        pp += __shfl_xor(pp, off);
        aa += __shfl_xor(aa, off);
        pa += __shfl_xor(pa, off);
    }
    float an  = sqrtf(aa);
    float inv = 1.0f / fmaxf(an, 1e-12f);
    for (int c = lane; c < C_DIM; c += 64) {
        ws[n * C_DIM + c] = A[n * C_DIM + c] * inv;   // normed_A
    }
    if (lane == 0) {
        ws[PP_OFF + n] = pp;
        ws[PA_OFF + n] = -pa * inv;   // sum(-P * normed_A)
        ws[AN_OFF + n] = an;          // ||A_n||
    }
}

// ---------------- main: 1 pixel per thread, full C reduction ---------------
__global__ __launch_bounds__(256, 4) void hyper_mlr_main(
    const float* __restrict__ x, const float* __restrict__ P,
    const float* __restrict__ ws, float* __restrict__ out)
{
    __shared__ float4 sP4[N_DIM * CQ];   // -P, float4 over c
    __shared__ float4 sA4[N_DIM * CQ];   // normed_A
    __shared__ float  spp[N_DIM], spa[N_DIM], san[N_DIM];

    const float4* P4 = reinterpret_cast<const float4*>(P);
    const float4* W4 = reinterpret_cast<const float4*>(ws);
    for (int i = threadIdx.x; i < N_DIM * CQ; i += 256) {
        float4 pv = P4[i];
        sP4[i] = make_float4(-pv.x, -pv.y, -pv.z, -pv.w);
        sA4[i] = W4[i];
    }
    if (threadIdx.x < N_DIM) {
        spp[threadIdx.x] = ws[PP_OFF + threadIdx.x];
        spa[threadIdx.x] = ws[PA_OFF + threadIdx.x];
        san[threadIdx.x] = ws[AN_OFF + threadIdx.x];
    }
    __syncthreads();

    int tid = blockIdx.x * 256 + threadIdx.x;
    int b   = tid >> 16;
    int hw  = tid & 65535;
    const float* xb = x + (size_t)b * C_DIM * HW + hw;

    float xx = 0.f;
    float px[N_DIM], xa[N_DIM];
#pragma unroll
    for (int n = 0; n < N_DIM; ++n) { px[n] = 0.f; xa[n] = 0.f; }

    // software-pipelined c-loop, 4 channels per step
    float x0 = xb[0];
    float x1 = xb[(size_t)HW];
    float x2 = xb[(size_t)2 * HW];
    float x3 = xb[(size_t)3 * HW];

#pragma unroll 2
    for (int cq = 0; cq < CQ - 1; ++cq) {
        const float* xn = xb + (size_t)(cq + 1) * 4 * HW;
        float n0 = xn[0];
        float n1 = xn[(size_t)HW];
        float n2 = xn[(size_t)2 * HW];
        float n3 = xn[(size_t)3 * HW];

        xx += x0 * x0; xx += x1 * x1; xx += x2 * x2; xx += x3 * x3;
#pragma unroll
        for (int n = 0; n < N_DIM; ++n) {
            float4 p = sP4[n * CQ + cq];
            float4 a = sA4[n * CQ + cq];
            px[n] += x0 * p.x; px[n] += x1 * p.y; px[n] += x2 * p.z; px[n] += x3 * p.w;
            xa[n] += x0 * a.x; xa[n] += x1 * a.y; xa[n] += x2 * a.z; xa[n] += x3 * a.w;
        }
        x0 = n0; x1 = n1; x2 = n2; x3 = n3;
    }
    {   // last c-quad
        const int cq = CQ - 1;
        xx += x0 * x0; xx += x1 * x1; xx += x2 * x2; xx += x3 * x3;
#pragma unroll
        for (int n = 0; n < N_DIM; ++n) {
            float4 p = sP4[n * CQ + cq];
            float4 a = sA4[n * CQ + cq];
            px[n] += x0 * p.x; px[n] += x1 * p.y; px[n] += x2 * p.z; px[n] += x3 * p.w;
            xa[n] += x0 * a.x; xa[n] += x1 * a.y; xa[n] += x2 * a.z; xa[n] += x3 * a.w;
        }
    }

    const float K        = 0.5f;
    const float sqK      = 0.70710678118654752f;          // sqrt(K)
    const float maxnorm  = 0.999f / sqK;                  // (1-PROJ_EPS)/sqrt(K)
    const float maxnorm2 = maxnorm * maxnorm;
    const float eps      = 1e-12f;

    float* ob = out + (size_t)b * N_DIM * HW + hw;
#pragma unroll
    for (int n = 0; n < N_DIM; ++n) {
        float pp = spp[n];
        float pa = spa[n];
        float an = san[n];
        float pxs = px[n], xas = xa[n];

        float Av = 1.0f + pxs + K * xx;                   // 2K = 1
        float Bv = 1.0f - K * pp;
        float D  = fmaxf(1.0f + pxs + (K * K) * xx * pp, eps);
        float alpha = Av / D, beta = Bv / D;
        float mob = alpha * alpha * pp + beta * beta * xx + 2.0f * alpha * beta * pxs;
        float sqrtm = sqrtf(fmaxf(mob, 0.0f));
        float proj = (sqrtm > maxnorm) ? (maxnorm / fmaxf(sqrtm, eps)) : 1.0f;
        float mobp = (sqrtm < maxnorm) ? mob : maxnorm2;
        float mobdota = (beta * xas + alpha * pa) * proj;
        float lamb = 2.0f / fmaxf(1.0f - K * mobp, eps);
        float sine = sqK * mobdota * lamb;
        ob[(size_t)n * HW] = (2.0f / sqK) * an * asinhf(sine);
    }
}

extern "C" void kernel_launch(void* const* d_in, const int* in_sizes, int n_in,
                              void* d_out, int out_size, void* d_ws, size_t ws_size,
                              hipStream_t stream) {
    const float* x  = (const float*)d_in[0];
    const float* P  = (const float*)d_in[1];
    const float* A  = (const float*)d_in[2];
    float* out = (float*)d_out;
    float* ws  = (float*)d_ws;

    prep_kernel<<<N_DIM, 64, 0, stream>>>(P, A, ws);
    hyper_mlr_main<<<1024, 256, 0, stream>>>(x, P, ws, out);
}